// Round 3
// baseline (4252.538 us; speedup 1.0000x reference)
//
#include <hip/hip_runtime.h>
#include <math.h>

#define DIM    256
#define K_EMB  1024
#define HW     4096
#define CHW    1048576
#define N_TOK  65536
#define NELEM  16777216

// d_out float offsets
#define OUT_LOSS 0
#define OUT_ZQ   1
#define OUT_PERP 16777217
#define OUT_MENC 16777218LL
#define OUT_IDX  83886082

#define ZPAD 260    // 256 + 4 pad; row stride 1040 B keeps 16B alignment for b128
#define TAU  1e-4f  // flag margin: > 3x fp32 quantum at |z|^2~256 + distortion bounds

// ---- numpy pairwise summation, exact replication for n=256 ----
// numpy: n=256 -> split 128+128; each 128-block: 8 strided accumulators,
// combine ((r0+r1)+(r2+r3))+((r4+r5)+(r6+r7)); total = left + right.
__device__ __forceinline__ float np_pair128(const float* p) {
    float r[8];
    #pragma unroll
    for (int j = 0; j < 8; ++j) r[j] = p[j];
    for (int i = 8; i < 128; i += 8)
        #pragma unroll
        for (int j = 0; j < 8; ++j) r[j] = __fadd_rn(r[j], p[i + j]);
    return __fadd_rn(__fadd_rn(__fadd_rn(r[0], r[1]), __fadd_rn(r[2], r[3])),
                     __fadd_rn(__fadd_rn(r[4], r[5]), __fadd_rn(r[6], r[7])));
}
__device__ __forceinline__ float np_pair256(const float* p) {
    return __fadd_rn(np_pair128(p), np_pair128(p + 128));
}

// ---------------- t2[k] = np-exact fp32 row norms of embed ----------------
__global__ void t2_np_kernel(const float* __restrict__ embed, float* __restrict__ t2) {
    int k = blockIdx.x * 256 + threadIdx.x;   // 1024 threads total
    if (k >= K_EMB) return;
    const float* e = embed + (size_t)k * DIM;
    float p[256];
    for (int c = 0; c < DIM; c += 4) {
        float4 v = *(const float4*)(e + c);
        p[c]     = __fmul_rn(v.x, v.x);
        p[c + 1] = __fmul_rn(v.y, v.y);
        p[c + 2] = __fmul_rn(v.z, v.z);
        p[c + 3] = __fmul_rn(v.w, v.w);
    }
    t2[k] = np_pair256(p);
}

// ---------------- main: fp32 score + argmin + ambiguity flagging ----------------
// grid 2048 = B*H*2 ; block handles 32 tokens (half a w-row)
__launch_bounds__(256)
__global__ void vq_main(const float* __restrict__ z, const float* __restrict__ embed,
                        const float* __restrict__ t2g, float* __restrict__ out,
                        unsigned int* __restrict__ nflag) {
    __shared__ __align__(16) float z_lds[32 * ZPAD];
    __shared__ float norm_lds[K_EMB];
    __shared__ float red_s[32][16];
    __shared__ float red_s2[32][16];
    __shared__ int   red_k[32][16];

    const int tid = threadIdx.x;
    const int blk = blockIdx.x;           // = b*128 + h*2 + wh
    const int b   = blk >> 7;
    const int h   = (blk >> 1) & 63;
    const int wh  = blk & 1;
    const float* zbase = z + (size_t)b * CHW + h * 64 + wh * 32;

    for (int i = tid; i < DIM * 32; i += 256) {
        int c = i >> 5, w = i & 31;
        z_lds[w * ZPAD + c] = zbase[(size_t)c * HW + w];
    }
    for (int i = tid; i < K_EMB; i += 256) norm_lds[i] = t2g[i];
    __syncthreads();

    const int q  = tid & 15;      // k partition
    const int wp = tid >> 4;      // token pair
    const int w0 = wp * 2, w1 = w0 + 1;
    const float* zl0 = z_lds + w0 * ZPAD;
    const float* zl1 = z_lds + w1 * ZPAD;

    float bs0 = 3.4e38f, bs1 = 3.4e38f;   // best
    float ss0 = 3.4e38f, ss1 = 3.4e38f;   // second best
    int   bk0 = 0, bk1 = 0;
    const int kbase = q * 64;

    for (int kk = 0; kk < 64; kk += 8) {
        float d0[8], d1[8];
        #pragma unroll
        for (int j = 0; j < 8; ++j) { d0[j] = 0.0f; d1[j] = 0.0f; }
        const float* e0 = embed + (size_t)(kbase + kk) * DIM;
        for (int c = 0; c < DIM; c += 4) {
            float4 zv0 = *(const float4*)(zl0 + c);
            float4 zv1 = *(const float4*)(zl1 + c);
            #pragma unroll
            for (int j = 0; j < 8; ++j) {
                float4 e4 = *(const float4*)(e0 + j * DIM + c);
                d0[j] = fmaf(zv0.x, e4.x, d0[j]);
                d0[j] = fmaf(zv0.y, e4.y, d0[j]);
                d0[j] = fmaf(zv0.z, e4.z, d0[j]);
                d0[j] = fmaf(zv0.w, e4.w, d0[j]);
                d1[j] = fmaf(zv1.x, e4.x, d1[j]);
                d1[j] = fmaf(zv1.y, e4.y, d1[j]);
                d1[j] = fmaf(zv1.z, e4.z, d1[j]);
                d1[j] = fmaf(zv1.w, e4.w, d1[j]);
            }
        }
        #pragma unroll
        for (int j = 0; j < 8; ++j) {
            int k = kbase + kk + j;
            float nv = norm_lds[k];
            float s0 = fmaf(-2.0f, d0[j], nv);   // |e|^2 - 2 z.e (|z|^2 omitted: rank-invariant)
            float s1 = fmaf(-2.0f, d1[j], nv);
            if (s0 < bs0)      { ss0 = bs0; bs0 = s0; bk0 = k; }
            else if (s0 < ss0) { ss0 = s0; }
            if (s1 < bs1)      { ss1 = bs1; bs1 = s1; bk1 = k; }
            else if (s1 < ss1) { ss1 = s1; }
        }
    }

    red_s [w0][q] = bs0; red_s2[w0][q] = ss0; red_k[w0][q] = bk0;
    red_s [w1][q] = bs1; red_s2[w1][q] = ss1; red_k[w1][q] = bk1;
    __syncthreads();

    if (tid < 32) {
        int w = tid;
        float bs = 3.4e38f, ss = 3.4e38f;
        int bk = 0;
        #pragma unroll
        for (int j = 0; j < 16; ++j) {          // ascending j == ascending k
            float s1 = red_s[w][j];
            if (s1 < bs) { ss = fminf(bs, red_s2[w][j]); bs = s1; bk = red_k[w][j]; }
            else if (s1 < ss) { ss = s1; }
        }
        int n = blk * 32 + w;
        out[OUT_IDX + n] = (float)bk;
        if (ss - bs < TAU) {                    // quantization could decide -> np-exact rescore
            unsigned int slot = atomicAdd(nflag, 1u);
            ((int*)(out + OUT_MENC))[slot] = n; // scratch in not-yet-written min_enc region
        }
    }
}

// ---------------- np-exact fp32-quantized rescoring of flagged tokens ----------------
// d_k = fl32( fl32(t1 + t2_k) - 2*fl32(z.e_k) ), argmin with lowest-k tie-break.
__global__ void refine_np_kernel(const float* __restrict__ z, const float* __restrict__ embed,
                                 const float* __restrict__ t2g, float* __restrict__ out,
                                 const unsigned int* __restrict__ nflag) {
    __shared__ float  zs[DIM];
    __shared__ double zd[DIM];
    __shared__ float  pp[DIM];
    __shared__ float  t1s;
    __shared__ float  rs[256];
    __shared__ int    rk[256];
    const int tid = threadIdx.x;
    const int nf = (int)*nflag;
    const int* flags = (const int*)(out + OUT_MENC);

    for (int i = blockIdx.x; i < nf; i += gridDim.x) {
        int n   = flags[i];
        int b   = n >> 12;
        int rem = n & 4095;
        const float* zt = z + (size_t)b * CHW + rem;
        __syncthreads();                         // protect shared from previous iter
        float zv = zt[(size_t)tid * HW];
        zs[tid] = zv;
        zd[tid] = (double)zv;
        pp[tid] = __fmul_rn(zv, zv);
        __syncthreads();
        if (tid == 0) t1s = np_pair256(pp);      // numpy-exact |z|^2
        __syncthreads();
        const float t1 = t1s;

        float bd = 3.4e38f; int bk = 0;
        #pragma unroll 1
        for (int j = 0; j < 4; ++j) {
            int k = tid * 4 + j;                 // ascending within thread
            const float* e = embed + (size_t)k * DIM;
            double s = 0.0;
            for (int c = 0; c < DIM; ++c) s = fma(zd[c], (double)e[c], s);
            float rho = (float)s;                // correctly-rounded fp32 dot
            float d = __fadd_rn(__fadd_rn(t1, t2g[k]), -__fmul_rn(2.0f, rho));
            if (d < bd) { bd = d; bk = k; }      // strict <: lowest k on ties
        }
        rs[tid] = bd; rk[tid] = bk;
        __syncthreads();
        for (int st = 128; st > 0; st >>= 1) {
            if (tid < st) {
                float so = rs[tid + st]; int ko = rk[tid + st];
                if (so < rs[tid] || (so == rs[tid] && ko < rk[tid])) { rs[tid] = so; rk[tid] = ko; }
            }
            __syncthreads();
        }
        if (tid == 0) out[OUT_IDX + n] = (float)rk[0];
    }
}

// ---------------- z_q gather + NCHW store + loss + counts (from FINAL idx) ----------------
__launch_bounds__(256)
__global__ void zq_loss_kernel(const float* __restrict__ z, const float* __restrict__ embed,
                               float* __restrict__ out, unsigned int* __restrict__ counts,
                               float* __restrict__ loss_sum) {
    const int tid = threadIdx.x;
    const int blk = blockIdx.x;
    const int b   = blk >> 7;
    const int h   = (blk >> 1) & 63;
    const int wh  = blk & 1;
    const int w   = tid & 31;
    const int cs  = tid >> 5;                   // 0..7
    const int n   = blk * 32 + w;

    const int myk = (int)out[OUT_IDX + n];
    if (tid < 32) atomicAdd(&counts[myk], 1u);

    const float* erow = embed + (size_t)myk * DIM;
    const float* zt = z   + (size_t)b * CHW + h * 64 + wh * 32;
    float*       zq = out + OUT_ZQ + (size_t)b * CHW + h * 64 + wh * 32;
    float lsum = 0.0f;
    for (int c = cs; c < DIM; c += 8) {
        float v  = erow[c];
        float dz = v - zt[(size_t)c * HW + w];
        lsum = fmaf(dz, dz, lsum);
        zq[(size_t)c * HW + w] = v;
    }
    #pragma unroll
    for (int off = 32; off > 0; off >>= 1) lsum += __shfl_down(lsum, off, 64);
    if ((tid & 63) == 0) atomicAdd(loss_sum, lsum);
}

// ---------------- one-hot encodings: 256 MB of float2 stores ----------------
__global__ void min_enc_kernel(float* __restrict__ out) {
    long long gid = (long long)blockIdx.x * 256 + threadIdx.x;   // 0..33554431
    int n  = (int)(gid >> 9);
    int j2 = (int)(gid & 511);
    int k0 = j2 << 1;
    int id = (int)out[OUT_IDX + n];
    float2 v;
    v.x = (k0     == id) ? 1.0f : 0.0f;
    v.y = (k0 + 1 == id) ? 1.0f : 0.0f;
    *(float2*)(out + OUT_MENC + (long long)n * K_EMB + k0) = v;
}

// ---------------- loss scale + perplexity ----------------
__global__ void finalize_kernel(const unsigned int* __restrict__ counts,
                                const float* __restrict__ loss_sum,
                                float* __restrict__ out) {
    __shared__ float red[256];
    int tid = threadIdx.x;
    float hsum = 0.0f;
    for (int k = tid; k < K_EMB; k += 256) {
        float p = (float)counts[k] * (1.0f / 65536.0f);
        hsum += p * logf(p + 1e-10f);
    }
    red[tid] = hsum;
    __syncthreads();
    for (int s = 128; s > 0; s >>= 1) {
        if (tid < s) red[tid] += red[tid + s];
        __syncthreads();
    }
    if (tid == 0) {
        out[OUT_PERP] = expf(-red[0]);
        out[OUT_LOSS] = loss_sum[0] * 1.25f * (1.0f / (float)NELEM);
    }
}

extern "C" void kernel_launch(void* const* d_in, const int* in_sizes, int n_in,
                              void* d_out, int out_size, void* d_ws, size_t ws_size,
                              hipStream_t stream) {
    const float* z     = (const float*)d_in[0];
    const float* embed = (const float*)d_in[1];
    float* out = (float*)d_out;

    unsigned int* counts = (unsigned int*)d_ws;                  // 1024 * u32
    float* loss_sum      = (float*)((char*)d_ws + 4096);         // 1 float
    unsigned int* nflag  = (unsigned int*)((char*)d_ws + 4100);  // 1 u32
    float* t2g           = (float*)((char*)d_ws + 8192);         // 1024 floats

    hipMemsetAsync(d_ws, 0, 4104, stream);                       // counts + loss_sum + nflag
    t2_np_kernel    <<<dim3(4),      dim3(256), 0, stream>>>(embed, t2g);
    vq_main         <<<dim3(2048),   dim3(256), 0, stream>>>(z, embed, t2g, out, nflag);
    refine_np_kernel<<<dim3(256),    dim3(256), 0, stream>>>(z, embed, t2g, out, nflag);
    zq_loss_kernel  <<<dim3(2048),   dim3(256), 0, stream>>>(z, embed, out, counts, loss_sum);
    min_enc_kernel  <<<dim3(131072), dim3(256), 0, stream>>>(out);
    finalize_kernel <<<dim3(1),      dim3(256), 0, stream>>>(counts, loss_sum, out);
}

// Round 4
// 973.767 us; speedup vs baseline: 4.3671x; 4.3671x over previous
//
#include <hip/hip_runtime.h>
#include <math.h>

#define DIM    256
#define K_EMB  1024
#define HW     4096
#define CHW    1048576
#define N_TOK  65536
#define NELEM  16777216

// d_out float offsets
#define OUT_LOSS 0
#define OUT_ZQ   1
#define OUT_PERP 16777217
#define OUT_MENC 16777218LL
#define OUT_IDX  83886082

#define TAU  1.5e-4f  // bf16-split fast-pass error sigma ~1e-5 -> 8+ sigma safety

typedef short short8  __attribute__((ext_vector_type(8)));
typedef float floatx4 __attribute__((ext_vector_type(4)));

// Scratch layout inside the (written-last) min_encodings region, float units
// from scr = out + OUT_MENC. OUT_MENC % 4 == 2, so offsets ≡ 2 (mod 4) are
// 16B-aligned.
#define A_OFF     2LL                       // A' = [zh|zl] 65536 x 512 bf16 (64 MB)
#define EH_OFF    (A_OFF + 16777216LL)      // eh 1024 x 256 bf16 (512 KB)
#define FLAGS_OFF (EH_OFF + 131072LL)       // flag list (<= 65536 ints)

__device__ __forceinline__ unsigned short f2bf(float f) {  // RNE fp32->bf16
    unsigned int u = __float_as_uint(f);
    return (unsigned short)((u + 0x7FFFu + ((u >> 16) & 1u)) >> 16);
}
__device__ __forceinline__ float bf2f(unsigned short h) {
    return __uint_as_float(((unsigned int)h) << 16);
}

// ---- numpy pairwise summation, exact replication for n=256 ----
__device__ __forceinline__ float np_pair128(const float* p) {
    float r[8];
    #pragma unroll
    for (int j = 0; j < 8; ++j) r[j] = p[j];
    for (int i = 8; i < 128; i += 8)
        #pragma unroll
        for (int j = 0; j < 8; ++j) r[j] = __fadd_rn(r[j], p[i + j]);
    return __fadd_rn(__fadd_rn(__fadd_rn(r[0], r[1]), __fadd_rn(r[2], r[3])),
                     __fadd_rn(__fadd_rn(r[4], r[5]), __fadd_rn(r[6], r[7])));
}
__device__ __forceinline__ float np_pair256(const float* p) {
    return __fadd_rn(np_pair128(p), np_pair128(p + 128));
}

// ---------------- t2[k] (np-exact) + eh bf16 rows ----------------
__global__ void t2_np_kernel(const float* __restrict__ embed, float* __restrict__ t2,
                             unsigned short* __restrict__ Eh) {
    int k = blockIdx.x * 256 + threadIdx.x;
    if (k >= K_EMB) return;
    const float* e = embed + (size_t)k * DIM;
    float p[256];
    for (int c = 0; c < DIM; c += 4) {
        float4 v = *(const float4*)(e + c);
        p[c]     = __fmul_rn(v.x, v.x);
        p[c + 1] = __fmul_rn(v.y, v.y);
        p[c + 2] = __fmul_rn(v.z, v.z);
        p[c + 3] = __fmul_rn(v.w, v.w);
    }
    t2[k] = np_pair256(p);
    unsigned short* dst = Eh + (size_t)k * DIM;
    for (int c0 = 0; c0 < DIM; c0 += 8) {
        short8 vh;
        #pragma unroll
        for (int u = 0; u < 8; ++u) vh[u] = (short)f2bf(e[c0 + u]);
        *(short8*)(dst + c0) = vh;
    }
}

// ---------------- z NCHW -> A' = [zh|zl] bf16 [n][512] ----------------
// grid 1024 (64 tokens/block), 256 thr: lane = w (coalesced z reads)
__global__ void prep_z(const float* __restrict__ z, unsigned short* __restrict__ Ap) {
    const int tid = threadIdx.x;
    const int w   = tid & 63;
    const int j   = tid >> 6;                // 0..3, covers c in [j*64, j*64+64)
    const int n   = blockIdx.x * 64 + w;
    const int b   = n >> 12;
    const int rem = n & 4095;
    const float* zp = z + (size_t)b * CHW + rem;
    unsigned short* dst = Ap + (size_t)n * 512;
    for (int g = 0; g < 8; ++g) {
        int c0 = j * 64 + g * 8;
        short8 vh, vl;
        #pragma unroll
        for (int u = 0; u < 8; ++u) {
            float v = zp[(size_t)(c0 + u) * HW];
            unsigned short h = f2bf(v);
            vh[u] = (short)h;
            vl[u] = (short)f2bf(v - bf2f(h));
        }
        *(short8*)(dst + c0)       = vh;
        *(short8*)(dst + 256 + c0) = vl;
    }
}

// ---------------- MFMA fast pass: scores + top-2 + flagging ----------------
// grid 1024 blocks x 256 thr; block = 64 tokens, loops all 1024 codes.
__launch_bounds__(256, 4)
__global__ void vq_mfma(const unsigned short* __restrict__ Ap,
                        const unsigned short* __restrict__ Eh,
                        const float* __restrict__ t2g,
                        float* __restrict__ out,
                        unsigned int* __restrict__ nflag,
                        int* __restrict__ flags) {
    __shared__ unsigned short lds_b[32 * 264];   // 32 codes x 256 bf16, pad 8
    __shared__ float t2_lds[K_EMB];

    const int tid  = threadIdx.x;
    const int lane = tid & 63;
    const int wv   = tid >> 6;
    const int l15  = lane & 15;
    const int quad = lane >> 4;
    const int m0   = blockIdx.x * 64;

    for (int i = tid; i < K_EMB; i += 256) t2_lds[i] = t2g[i];

    // A-frags resident: 16 k-chunks (8 zh + 8 zl)
    short8 a[16];
    const short8* arow = (const short8*)(Ap + (size_t)(m0 + wv * 16 + l15) * 512);
    #pragma unroll
    for (int kc = 0; kc < 16; ++kc) a[kc] = arow[kc * 4 + quad];

    float bs[4], ss[4]; int bk[4];
    #pragma unroll
    for (int r = 0; r < 4; ++r) { bs[r] = 3.4e38f; ss[r] = 3.4e38f; bk[r] = 0; }

    const int srow = tid >> 3;            // staging: 32 rows x 256 bf16
    const int scol = (tid & 7) * 32;

    for (int it = 0; it < 32; ++it) {
        const int n0 = it * 32;
        __syncthreads();
        {
            const short8* g = (const short8*)(Eh + (size_t)(n0 + srow) * 256 + scol);
            short8* l = (short8*)(lds_b + srow * 264 + scol);
            short8 v0 = g[0], v1 = g[1], v2 = g[2], v3 = g[3];
            l[0] = v0; l[1] = v1; l[2] = v2; l[3] = v3;
        }
        __syncthreads();
        floatx4 acc0 = {0.f, 0.f, 0.f, 0.f};
        floatx4 acc1 = {0.f, 0.f, 0.f, 0.f};
        #pragma unroll
        for (int kc = 0; kc < 8; ++kc) {
            short8 b0 = *(const short8*)(lds_b + l15 * 264 + kc * 32 + quad * 8);
            short8 b1 = *(const short8*)(lds_b + (16 + l15) * 264 + kc * 32 + quad * 8);
            acc0 = __builtin_amdgcn_mfma_f32_16x16x32_bf16(a[kc],     b0, acc0, 0, 0, 0);
            acc1 = __builtin_amdgcn_mfma_f32_16x16x32_bf16(a[kc],     b1, acc1, 0, 0, 0);
            acc0 = __builtin_amdgcn_mfma_f32_16x16x32_bf16(a[8 + kc], b0, acc0, 0, 0, 0);
            acc1 = __builtin_amdgcn_mfma_f32_16x16x32_bf16(a[8 + kc], b1, acc1, 0, 0, 0);
        }
        float t20 = t2_lds[n0 + l15];
        float t21 = t2_lds[n0 + 16 + l15];
        #pragma unroll
        for (int r = 0; r < 4; ++r) {
            float s0 = fmaf(-2.0f, acc0[r], t20);   // |e|^2 - 2 z.e
            if (s0 < bs[r]) { ss[r] = bs[r]; bs[r] = s0; bk[r] = n0 + l15; }
            else if (s0 < ss[r]) ss[r] = s0;
            float s1 = fmaf(-2.0f, acc1[r], t21);
            if (s1 < bs[r]) { ss[r] = bs[r]; bs[r] = s1; bk[r] = n0 + 16 + l15; }
            else if (s1 < ss[r]) ss[r] = s1;
        }
    }

    // merge top-2 across the 16 lanes of each quad (token = quad*4 + r)
    #pragma unroll
    for (int r = 0; r < 4; ++r) {
        for (int mo = 1; mo < 16; mo <<= 1) {
            float obs = __shfl_xor(bs[r], mo, 64);
            float oss = __shfl_xor(ss[r], mo, 64);
            int   obk = __shfl_xor(bk[r], mo, 64);
            if (obs < bs[r] || (obs == bs[r] && obk < bk[r])) {
                ss[r] = fminf(bs[r], oss); bs[r] = obs; bk[r] = obk;
            } else {
                ss[r] = fminf(ss[r], obs);
            }
        }
        if (l15 == 0) {
            int ntok = m0 + wv * 16 + quad * 4 + r;
            out[OUT_IDX + ntok] = (float)bk[r];
            if (ss[r] - bs[r] < TAU) {
                unsigned int slot = atomicAdd(nflag, 1u);
                flags[slot] = ntok;
            }
        }
    }
}

// ---------------- np-exact fp32-quantized rescoring of flagged tokens ----------------
__global__ void refine_np_kernel(const float* __restrict__ z, const float* __restrict__ embed,
                                 const float* __restrict__ t2g, float* __restrict__ out,
                                 const unsigned int* __restrict__ nflag,
                                 const int* __restrict__ flags) {
    __shared__ double zd[DIM];
    __shared__ float  pp[DIM];
    __shared__ float  t1s;
    __shared__ float  rs[256];
    __shared__ int    rk[256];
    const int tid = threadIdx.x;
    const int nf = (int)*nflag;

    for (int i = blockIdx.x; i < nf; i += gridDim.x) {
        int n   = flags[i];
        int b   = n >> 12;
        int rem = n & 4095;
        const float* zt = z + (size_t)b * CHW + rem;
        __syncthreads();
        float zv = zt[(size_t)tid * HW];
        zd[tid] = (double)zv;
        pp[tid] = __fmul_rn(zv, zv);
        __syncthreads();
        if (tid == 0) t1s = np_pair256(pp);
        __syncthreads();
        const float t1 = t1s;

        float bd = 3.4e38f; int bkk = 0;
        #pragma unroll 1
        for (int j = 0; j < 4; ++j) {
            int k = tid * 4 + j;
            const float* e = embed + (size_t)k * DIM;
            double s = 0.0;
            for (int c = 0; c < DIM; ++c) s = fma(zd[c], (double)e[c], s);
            float rho = (float)s;
            float d = __fadd_rn(__fadd_rn(t1, t2g[k]), -__fmul_rn(2.0f, rho));
            if (d < bd) { bd = d; bkk = k; }
        }
        rs[tid] = bd; rk[tid] = bkk;
        __syncthreads();
        for (int st = 128; st > 0; st >>= 1) {
            if (tid < st) {
                float so = rs[tid + st]; int ko = rk[tid + st];
                if (so < rs[tid] || (so == rs[tid] && ko < rk[tid])) { rs[tid] = so; rk[tid] = ko; }
            }
            __syncthreads();
        }
        if (tid == 0) out[OUT_IDX + n] = (float)rk[0];
    }
}

// ---------------- z_q gather + NCHW store + loss + counts ----------------
__launch_bounds__(256)
__global__ void zq_loss_kernel(const float* __restrict__ z, const float* __restrict__ embed,
                               float* __restrict__ out, unsigned int* __restrict__ counts,
                               float* __restrict__ loss_sum) {
    const int tid = threadIdx.x;
    const int blk = blockIdx.x;
    const int b   = blk >> 7;
    const int h   = (blk >> 1) & 63;
    const int wh  = blk & 1;
    const int w   = tid & 31;
    const int cs  = tid >> 5;
    const int n   = blk * 32 + w;

    const int myk = (int)out[OUT_IDX + n];
    if (tid < 32) atomicAdd(&counts[myk], 1u);

    const float* erow = embed + (size_t)myk * DIM;
    const float* zt = z   + (size_t)b * CHW + h * 64 + wh * 32;
    float*       zq = out + OUT_ZQ + (size_t)b * CHW + h * 64 + wh * 32;
    float lsum = 0.0f;
    for (int c = cs; c < DIM; c += 8) {
        float v  = erow[c];
        float dz = v - zt[(size_t)c * HW + w];
        lsum = fmaf(dz, dz, lsum);
        zq[(size_t)c * HW + w] = v;
    }
    #pragma unroll
    for (int off = 32; off > 0; off >>= 1) lsum += __shfl_down(lsum, off, 64);
    if ((tid & 63) == 0) atomicAdd(loss_sum, lsum);
}

// ---------------- one-hot encodings: 256 MB of float2 stores ----------------
__global__ void min_enc_kernel(float* __restrict__ out) {
    long long gid = (long long)blockIdx.x * 256 + threadIdx.x;
    int n  = (int)(gid >> 9);
    int j2 = (int)(gid & 511);
    int k0 = j2 << 1;
    int id = (int)out[OUT_IDX + n];
    float2 v;
    v.x = (k0     == id) ? 1.0f : 0.0f;
    v.y = (k0 + 1 == id) ? 1.0f : 0.0f;
    *(float2*)(out + OUT_MENC + (long long)n * K_EMB + k0) = v;
}

// ---------------- loss scale + perplexity ----------------
__global__ void finalize_kernel(const unsigned int* __restrict__ counts,
                                const float* __restrict__ loss_sum,
                                float* __restrict__ out) {
    __shared__ float red[256];
    int tid = threadIdx.x;
    float hsum = 0.0f;
    for (int k = tid; k < K_EMB; k += 256) {
        float p = (float)counts[k] * (1.0f / 65536.0f);
        hsum += p * logf(p + 1e-10f);
    }
    red[tid] = hsum;
    __syncthreads();
    for (int s = 128; s > 0; s >>= 1) {
        if (tid < s) red[tid] += red[tid + s];
        __syncthreads();
    }
    if (tid == 0) {
        out[OUT_PERP] = expf(-red[0]);
        out[OUT_LOSS] = loss_sum[0] * 1.25f * (1.0f / (float)NELEM);
    }
}

extern "C" void kernel_launch(void* const* d_in, const int* in_sizes, int n_in,
                              void* d_out, int out_size, void* d_ws, size_t ws_size,
                              hipStream_t stream) {
    const float* z     = (const float*)d_in[0];
    const float* embed = (const float*)d_in[1];
    float* out = (float*)d_out;

    unsigned int* counts = (unsigned int*)d_ws;                  // 1024 * u32
    float* loss_sum      = (float*)((char*)d_ws + 4096);
    unsigned int* nflag  = (unsigned int*)((char*)d_ws + 4100);
    float* t2g           = (float*)((char*)d_ws + 8192);         // 1024 floats

    float* scr = out + OUT_MENC;                                 // scratch in min_enc region
    unsigned short* Ap = (unsigned short*)(scr + A_OFF);
    unsigned short* Eh = (unsigned short*)(scr + EH_OFF);
    int*            fl = (int*)(scr + FLAGS_OFF);

    hipMemsetAsync(d_ws, 0, 4104, stream);
    t2_np_kernel    <<<dim3(4),      dim3(256), 0, stream>>>(embed, t2g, Eh);
    prep_z          <<<dim3(1024),   dim3(256), 0, stream>>>(z, Ap);
    vq_mfma         <<<dim3(1024),   dim3(256), 0, stream>>>(Ap, Eh, t2g, out, nflag, fl);
    refine_np_kernel<<<dim3(512),    dim3(256), 0, stream>>>(z, embed, t2g, out, nflag, fl);
    zq_loss_kernel  <<<dim3(2048),   dim3(256), 0, stream>>>(z, embed, out, counts, loss_sum);
    min_enc_kernel  <<<dim3(131072), dim3(256), 0, stream>>>(out);
    finalize_kernel <<<dim3(1),      dim3(256), 0, stream>>>(counts, loss_sum, out);
}

// Round 5
// 783.216 us; speedup vs baseline: 5.4296x; 1.2433x over previous
//
#include <hip/hip_runtime.h>
#include <math.h>

#define DIM    256
#define K_EMB  1024
#define HW     4096
#define CHW    1048576
#define N_TOK  65536
#define NELEM  16777216

// d_out float offsets
#define OUT_LOSS 0
#define OUT_ZQ   1
#define OUT_PERP 16777217
#define OUT_MENC 16777218LL
#define OUT_IDX  83886082

#define TAU  1.5e-4f  // flag margin (proven r4)
#define WIN  6e-4f    // candidate window on bf16-stored scores (worst-case-safe)

typedef short short8  __attribute__((ext_vector_type(8)));
typedef float floatx4 __attribute__((ext_vector_type(4)));

// Scratch layout in the (written-last) min_encodings region, float units from
// scr = out + OUT_MENC. OUT_MENC % 4 == 2 -> offsets ≡ 2 (mod 4) are 16B-aligned.
#define A_OFF     2LL                       // A' = [zh|zl] 65536 x 512 bf16 (64 MB)
#define EH_OFF    (A_OFF + 16777216LL)      // eh 1024 x 256 bf16 (512 KB)
#define FLAGS_OFF (EH_OFF + 131072LL)       // flag list (<= 65536 ints)
#define SB_OFF    33554430LL                // scores 65536 x 1024 bf16 (128 MB), 16B-aligned

__device__ __forceinline__ unsigned short f2bf(float f) {  // RNE fp32->bf16
    unsigned int u = __float_as_uint(f);
    return (unsigned short)((u + 0x7FFFu + ((u >> 16) & 1u)) >> 16);
}
__device__ __forceinline__ float bf2f(unsigned short h) {
    return __uint_as_float(((unsigned int)h) << 16);
}

// ---- numpy pairwise summation, exact replication for n=256 (serial form) ----
__device__ __forceinline__ float np_pair128(const float* p) {
    float r[8];
    #pragma unroll
    for (int j = 0; j < 8; ++j) r[j] = p[j];
    for (int i = 8; i < 128; i += 8)
        #pragma unroll
        for (int j = 0; j < 8; ++j) r[j] = __fadd_rn(r[j], p[i + j]);
    return __fadd_rn(__fadd_rn(__fadd_rn(r[0], r[1]), __fadd_rn(r[2], r[3])),
                     __fadd_rn(__fadd_rn(r[4], r[5]), __fadd_rn(r[6], r[7])));
}
__device__ __forceinline__ float np_pair256(const float* p) {
    return __fadd_rn(np_pair128(p), np_pair128(p + 128));
}

// ---------------- t2[k] (np-exact) + eh bf16 rows ----------------
__global__ void t2_np_kernel(const float* __restrict__ embed, float* __restrict__ t2,
                             unsigned short* __restrict__ Eh) {
    int k = blockIdx.x * 256 + threadIdx.x;
    if (k >= K_EMB) return;
    const float* e = embed + (size_t)k * DIM;
    float p[256];
    for (int c = 0; c < DIM; c += 4) {
        float4 v = *(const float4*)(e + c);
        p[c]     = __fmul_rn(v.x, v.x);
        p[c + 1] = __fmul_rn(v.y, v.y);
        p[c + 2] = __fmul_rn(v.z, v.z);
        p[c + 3] = __fmul_rn(v.w, v.w);
    }
    t2[k] = np_pair256(p);
    unsigned short* dst = Eh + (size_t)k * DIM;
    for (int c0 = 0; c0 < DIM; c0 += 8) {
        short8 vh;
        #pragma unroll
        for (int u = 0; u < 8; ++u) vh[u] = (short)f2bf(e[c0 + u]);
        *(short8*)(dst + c0) = vh;
    }
}

// ---------------- z NCHW -> A' = [zh|zl] bf16 [n][512] ----------------
__global__ void prep_z(const float* __restrict__ z, unsigned short* __restrict__ Ap) {
    const int tid = threadIdx.x;
    const int w   = tid & 63;
    const int j   = tid >> 6;
    const int n   = blockIdx.x * 64 + w;
    const int b   = n >> 12;
    const int rem = n & 4095;
    const float* zp = z + (size_t)b * CHW + rem;
    unsigned short* dst = Ap + (size_t)n * 512;
    for (int g = 0; g < 8; ++g) {
        int c0 = j * 64 + g * 8;
        short8 vh, vl;
        #pragma unroll
        for (int u = 0; u < 8; ++u) {
            float v = zp[(size_t)(c0 + u) * HW];
            unsigned short h = f2bf(v);
            vh[u] = (short)h;
            vl[u] = (short)f2bf(v - bf2f(h));
        }
        *(short8*)(dst + c0)       = vh;
        *(short8*)(dst + 256 + c0) = vl;
    }
}

// ---------------- MFMA fast pass: scores + top-2 + flagging + score dump ----------------
__launch_bounds__(256, 4)
__global__ void vq_mfma(const unsigned short* __restrict__ Ap,
                        const unsigned short* __restrict__ Eh,
                        const float* __restrict__ t2g,
                        float* __restrict__ out,
                        unsigned int* __restrict__ nflag,
                        int* __restrict__ flags,
                        unsigned short* __restrict__ Sb) {
    __shared__ unsigned short lds_b[32 * 264];        // 32 codes x 256 bf16, pad 8
    __shared__ float t2_lds[K_EMB];
    __shared__ unsigned short score_lds[64 * 40];     // 64 tokens x 32 codes, pad->40

    const int tid  = threadIdx.x;
    const int lane = tid & 63;
    const int wv   = tid >> 6;
    const int l15  = lane & 15;
    const int quad = lane >> 4;
    const int m0   = blockIdx.x * 64;

    for (int i = tid; i < K_EMB; i += 256) t2_lds[i] = t2g[i];

    short8 a[16];
    const short8* arow = (const short8*)(Ap + (size_t)(m0 + wv * 16 + l15) * 512);
    #pragma unroll
    for (int kc = 0; kc < 16; ++kc) a[kc] = arow[kc * 4 + quad];

    float bs[4], ss[4]; int bk[4];
    float sc0[4], sc1[4];
    #pragma unroll
    for (int r = 0; r < 4; ++r) { bs[r] = 3.4e38f; ss[r] = 3.4e38f; bk[r] = 0; }

    const int srow = tid >> 3;
    const int scol = (tid & 7) * 32;
    const int tt = tid >> 2, ch = tid & 3;            // score-dump mapping

    for (int it = 0; it < 32; ++it) {
        const int n0 = it * 32;
        __syncthreads();
        {
            const short8* g = (const short8*)(Eh + (size_t)(n0 + srow) * 256 + scol);
            short8* l = (short8*)(lds_b + srow * 264 + scol);
            short8 v0 = g[0], v1 = g[1], v2 = g[2], v3 = g[3];
            l[0] = v0; l[1] = v1; l[2] = v2; l[3] = v3;
        }
        if (it > 0) {
            #pragma unroll
            for (int r = 0; r < 4; ++r) {
                int row = wv * 16 + quad * 4 + r;
                score_lds[row * 40 + l15]      = f2bf(sc0[r]);
                score_lds[row * 40 + 16 + l15] = f2bf(sc1[r]);
            }
        }
        __syncthreads();
        if (it > 0) {
            short8 v = *(short8*)(score_lds + tt * 40 + ch * 8);
            *(short8*)(Sb + (size_t)(m0 + tt) * 1024 + (n0 - 32) + ch * 8) = v;
        }
        floatx4 acc0 = {0.f, 0.f, 0.f, 0.f};
        floatx4 acc1 = {0.f, 0.f, 0.f, 0.f};
        #pragma unroll
        for (int kc = 0; kc < 8; ++kc) {
            short8 b0 = *(const short8*)(lds_b + l15 * 264 + kc * 32 + quad * 8);
            short8 b1 = *(const short8*)(lds_b + (16 + l15) * 264 + kc * 32 + quad * 8);
            acc0 = __builtin_amdgcn_mfma_f32_16x16x32_bf16(a[kc],     b0, acc0, 0, 0, 0);
            acc1 = __builtin_amdgcn_mfma_f32_16x16x32_bf16(a[kc],     b1, acc1, 0, 0, 0);
            acc0 = __builtin_amdgcn_mfma_f32_16x16x32_bf16(a[8 + kc], b0, acc0, 0, 0, 0);
            acc1 = __builtin_amdgcn_mfma_f32_16x16x32_bf16(a[8 + kc], b1, acc1, 0, 0, 0);
        }
        float t20 = t2_lds[n0 + l15];
        float t21 = t2_lds[n0 + 16 + l15];
        #pragma unroll
        for (int r = 0; r < 4; ++r) {
            float s0 = fmaf(-2.0f, acc0[r], t20);
            sc0[r] = s0;
            if (s0 < bs[r]) { ss[r] = bs[r]; bs[r] = s0; bk[r] = n0 + l15; }
            else if (s0 < ss[r]) ss[r] = s0;
            float s1 = fmaf(-2.0f, acc1[r], t21);
            sc1[r] = s1;
            if (s1 < bs[r]) { ss[r] = bs[r]; bs[r] = s1; bk[r] = n0 + 16 + l15; }
            else if (s1 < ss[r]) ss[r] = s1;
        }
    }
    // tail: dump it=31 scores
    __syncthreads();
    #pragma unroll
    for (int r = 0; r < 4; ++r) {
        int row = wv * 16 + quad * 4 + r;
        score_lds[row * 40 + l15]      = f2bf(sc0[r]);
        score_lds[row * 40 + 16 + l15] = f2bf(sc1[r]);
    }
    __syncthreads();
    {
        short8 v = *(short8*)(score_lds + tt * 40 + ch * 8);
        *(short8*)(Sb + (size_t)(m0 + tt) * 1024 + 992 + ch * 8) = v;
    }

    // merge top-2 across the 16 lanes of each quad (token = quad*4 + r)
    #pragma unroll
    for (int r = 0; r < 4; ++r) {
        for (int mo = 1; mo < 16; mo <<= 1) {
            float obs = __shfl_xor(bs[r], mo, 64);
            float oss = __shfl_xor(ss[r], mo, 64);
            int   obk = __shfl_xor(bk[r], mo, 64);
            if (obs < bs[r] || (obs == bs[r] && obk < bk[r])) {
                ss[r] = fminf(bs[r], oss); bs[r] = obs; bk[r] = obk;
            } else {
                ss[r] = fminf(ss[r], obs);
            }
        }
        if (l15 == 0) {
            int ntok = m0 + wv * 16 + quad * 4 + r;
            out[OUT_IDX + ntok] = (float)bk[r];
            if (ss[r] - bs[r] < TAU) {
                unsigned int slot = atomicAdd(nflag, 1u);
                flags[slot] = ntok;
            }
        }
    }
}

// ---------------- candidate-narrowed np-exact refine: one wave per flagged token ----------------
__launch_bounds__(256)
__global__ void refine_v2(const float* __restrict__ z, const float* __restrict__ embed,
                          const float* __restrict__ t2g, float* __restrict__ out,
                          const unsigned int* __restrict__ nflag,
                          const int* __restrict__ flags,
                          const unsigned short* __restrict__ Sb) {
    __shared__ float pp4[4][256];
    __shared__ int   ccnt[4];
    __shared__ int   clist[4][32];

    const int lane = threadIdx.x & 63;
    const int wv   = threadIdx.x >> 6;
    const int wid  = blockIdx.x * 4 + wv;
    const int nf   = (int)*nflag;

    for (int i = wid; i < nf; i += gridDim.x * 4) {
        const int n   = flags[i];
        const int b   = n >> 12;
        const int rem = n & 4095;

        // --- scan this token's bf16 score row: wave min, then candidates ---
        const unsigned short* srow = Sb + (size_t)n * 1024;
        short8 u0 = *(const short8*)(srow + lane * 16);
        short8 u1 = *(const short8*)(srow + lane * 16 + 8);
        float sv[16];
        #pragma unroll
        for (int j = 0; j < 8; ++j) { sv[j] = bf2f((unsigned short)u0[j]); sv[8 + j] = bf2f((unsigned short)u1[j]); }
        float lmin = sv[0];
        #pragma unroll
        for (int j = 1; j < 16; ++j) lmin = fminf(lmin, sv[j]);
        for (int mo = 1; mo < 64; mo <<= 1) lmin = fminf(lmin, __shfl_xor(lmin, mo, 64));
        const float thr = lmin + WIN;

        if (lane == 0) ccnt[wv] = 0;
        __asm__ volatile("s_waitcnt lgkmcnt(0)" ::: "memory");
        #pragma unroll
        for (int j = 0; j < 16; ++j) {
            if (sv[j] <= thr) {
                int pos = atomicAdd(&ccnt[wv], 1);
                if (pos < 32) clist[wv][pos] = lane * 16 + j;
            }
        }
        __asm__ volatile("s_waitcnt lgkmcnt(0)" ::: "memory");
        int cnt = ccnt[wv];
        if (cnt > 32) cnt = 32;

        // --- load z token (4 elems/lane), pp to LDS for np-exact t1 ---
        const float* zt = z + (size_t)b * CHW + rem;
        double zd[4]; float zf[4];
        #pragma unroll
        for (int u = 0; u < 4; ++u) {
            float v = zt[(size_t)(lane + u * 64) * HW];
            zf[u] = v; zd[u] = (double)v;
            pp4[wv][lane + u * 64] = __fmul_rn(v, v);
        }
        __asm__ volatile("s_waitcnt lgkmcnt(0)" ::: "memory");
        // numpy-pairwise t1: lanes 0..15 do the 8 strided accumulators per half
        float rj = 0.0f;
        if (lane < 16) {
            int jj = lane & 7, half = lane >> 3;
            const float* p = &pp4[wv][half * 128 + jj];
            rj = p[0];
            #pragma unroll
            for (int ii = 1; ii < 16; ++ii) rj = __fadd_rn(rj, p[ii * 8]);
        }
        float v0 = __shfl(rj, 0, 64), v1 = __shfl(rj, 1, 64), v2 = __shfl(rj, 2, 64), v3 = __shfl(rj, 3, 64);
        float v4 = __shfl(rj, 4, 64), v5 = __shfl(rj, 5, 64), v6 = __shfl(rj, 6, 64), v7 = __shfl(rj, 7, 64);
        float h0 = __fadd_rn(__fadd_rn(__fadd_rn(v0, v1), __fadd_rn(v2, v3)),
                             __fadd_rn(__fadd_rn(v4, v5), __fadd_rn(v6, v7)));
        v0 = __shfl(rj,  8, 64); v1 = __shfl(rj,  9, 64); v2 = __shfl(rj, 10, 64); v3 = __shfl(rj, 11, 64);
        v4 = __shfl(rj, 12, 64); v5 = __shfl(rj, 13, 64); v6 = __shfl(rj, 14, 64); v7 = __shfl(rj, 15, 64);
        float h1 = __fadd_rn(__fadd_rn(__fadd_rn(v0, v1), __fadd_rn(v2, v3)),
                             __fadd_rn(__fadd_rn(v4, v5), __fadd_rn(v6, v7)));
        const float t1 = __fadd_rn(h0, h1);

        // --- np-exact d for each candidate; argmin with lowest-k tie-break ---
        float bd = 3.4e38f; int bkk = 1 << 30;
        for (int ci = 0; ci < cnt; ++ci) {
            int k = clist[wv][ci];
            const float* e = embed + (size_t)k * DIM;
            double s = 0.0;
            #pragma unroll
            for (int u = 0; u < 4; ++u) s = fma(zd[u], (double)e[lane + u * 64], s);
            for (int mo = 1; mo < 64; mo <<= 1) s += __shfl_xor(s, mo, 64);
            float rho = (float)s;
            float d = __fadd_rn(__fadd_rn(t1, t2g[k]), -__fmul_rn(2.0f, rho));
            if (d < bd || (d == bd && k < bkk)) { bd = d; bkk = k; }
        }
        if (lane == 0) out[OUT_IDX + n] = (float)bkk;
    }
}

// ---------------- z_q gather + NCHW store + loss + counts ----------------
__launch_bounds__(256)
__global__ void zq_loss_kernel(const float* __restrict__ z, const float* __restrict__ embed,
                               float* __restrict__ out, unsigned int* __restrict__ counts,
                               float* __restrict__ loss_sum) {
    const int tid = threadIdx.x;
    const int blk = blockIdx.x;
    const int b   = blk >> 7;
    const int h   = (blk >> 1) & 63;
    const int wh  = blk & 1;
    const int w   = tid & 31;
    const int cs  = tid >> 5;
    const int n   = blk * 32 + w;

    const int myk = (int)out[OUT_IDX + n];
    if (tid < 32) atomicAdd(&counts[myk], 1u);

    const float* erow = embed + (size_t)myk * DIM;
    const float* zt = z   + (size_t)b * CHW + h * 64 + wh * 32;
    float*       zq = out + OUT_ZQ + (size_t)b * CHW + h * 64 + wh * 32;
    float lsum = 0.0f;
    for (int c = cs; c < DIM; c += 8) {
        float v  = erow[c];
        float dz = v - zt[(size_t)c * HW + w];
        lsum = fmaf(dz, dz, lsum);
        zq[(size_t)c * HW + w] = v;
    }
    #pragma unroll
    for (int off = 32; off > 0; off >>= 1) lsum += __shfl_down(lsum, off, 64);
    if ((tid & 63) == 0) atomicAdd(loss_sum, lsum);
}

// ---------------- one-hot encodings: 256 MB of float2 stores ----------------
__global__ void min_enc_kernel(float* __restrict__ out) {
    long long gid = (long long)blockIdx.x * 256 + threadIdx.x;
    int n  = (int)(gid >> 9);
    int j2 = (int)(gid & 511);
    int k0 = j2 << 1;
    int id = (int)out[OUT_IDX + n];
    float2 v;
    v.x = (k0     == id) ? 1.0f : 0.0f;
    v.y = (k0 + 1 == id) ? 1.0f : 0.0f;
    *(float2*)(out + OUT_MENC + (long long)n * K_EMB + k0) = v;
}

// ---------------- loss scale + perplexity ----------------
__global__ void finalize_kernel(const unsigned int* __restrict__ counts,
                                const float* __restrict__ loss_sum,
                                float* __restrict__ out) {
    __shared__ float red[256];
    int tid = threadIdx.x;
    float hsum = 0.0f;
    for (int k = tid; k < K_EMB; k += 256) {
        float p = (float)counts[k] * (1.0f / 65536.0f);
        hsum += p * logf(p + 1e-10f);
    }
    red[tid] = hsum;
    __syncthreads();
    for (int s = 128; s > 0; s >>= 1) {
        if (tid < s) red[tid] += red[tid + s];
        __syncthreads();
    }
    if (tid == 0) {
        out[OUT_PERP] = expf(-red[0]);
        out[OUT_LOSS] = loss_sum[0] * 1.25f * (1.0f / (float)NELEM);
    }
}

extern "C" void kernel_launch(void* const* d_in, const int* in_sizes, int n_in,
                              void* d_out, int out_size, void* d_ws, size_t ws_size,
                              hipStream_t stream) {
    const float* z     = (const float*)d_in[0];
    const float* embed = (const float*)d_in[1];
    float* out = (float*)d_out;

    unsigned int* counts = (unsigned int*)d_ws;                  // 1024 * u32
    float* loss_sum      = (float*)((char*)d_ws + 4096);
    unsigned int* nflag  = (unsigned int*)((char*)d_ws + 4100);
    float* t2g           = (float*)((char*)d_ws + 8192);         // 1024 floats

    float* scr = out + OUT_MENC;                                 // scratch in min_enc region
    unsigned short* Ap = (unsigned short*)(scr + A_OFF);
    unsigned short* Eh = (unsigned short*)(scr + EH_OFF);
    int*            fl = (int*)(scr + FLAGS_OFF);
    unsigned short* Sb = (unsigned short*)(scr + SB_OFF);

    hipMemsetAsync(d_ws, 0, 4104, stream);
    t2_np_kernel   <<<dim3(4),      dim3(256), 0, stream>>>(embed, t2g, Eh);
    prep_z         <<<dim3(1024),   dim3(256), 0, stream>>>(z, Ap);
    vq_mfma        <<<dim3(1024),   dim3(256), 0, stream>>>(Ap, Eh, t2g, out, nflag, fl, Sb);
    refine_v2      <<<dim3(512),    dim3(256), 0, stream>>>(z, embed, t2g, out, nflag, fl, Sb);
    zq_loss_kernel <<<dim3(2048),   dim3(256), 0, stream>>>(z, embed, out, counts, loss_sum);
    min_enc_kernel <<<dim3(131072), dim3(256), 0, stream>>>(out);
    finalize_kernel<<<dim3(1),      dim3(256), 0, stream>>>(counts, loss_sum, out);
}